// Round 6
// baseline (144.120 us; speedup 1.0000x reference)
//
#include <hip/hip_runtime.h>

#define BATCH   262144
#define IN_DIM  28
#define HID     128
#define LAT     64
#define NCODES  512
#define NBLK    256             // 1024 rows per block (16 waves x 64 rows)
#define WVS     16

// ---- quad-grouped LDS table geometry (strides proven r13/r14: 16B-aligned rows,
// 2-way bank aliasing = free). Element (row,k) at row*S + q*(K/4) + j*4 + e,
// where k = j*16 + q*4 + e. ----
#define S1 40     // lw1  [128][40]  K=32  (k 28 = folded b1, k 29..31 zero)
#define S2 136    // lw2/ld2 [..][136] K=128
#define SC 72     // lcb/ld1 [..][72]  K=64
#define O_LW1 0
#define O_LW2 5120
#define O_LCB 13824
#define O_LD1 50688
#define O_LD2 59904
#define BLOB_SHORTS 64256
// f32 region: e2[512] @0, b2[64] @512, db1[128] @576, db2[32] @704
#define BLOB_F32    736
#define BLOB_BYTES  (BLOB_SHORTS * 2 + BLOB_F32 * 4)   // 131456
#define LDS_BYTES   BLOB_BYTES

typedef short v4s __attribute__((ext_vector_type(4)));
typedef short v8s __attribute__((ext_vector_type(8)));
typedef float v4f __attribute__((ext_vector_type(4)));

union u2v4 { unsigned u[2]; v4s s; };

__device__ __forceinline__ unsigned short f2bf(float f) {   // RNE (prep only)
  unsigned u = __float_as_uint(f);
  u += 0x7fffu + ((u >> 16) & 1u);
  return (unsigned short)(u >> 16);
}
// pack two truncated bf16 (hi, lo) in ONE v_perm_b32 (truncation validated r7/r8)
__device__ __forceinline__ unsigned pk(float hi, float lo) {
  return __builtin_amdgcn_perm(__float_as_uint(hi), __float_as_uint(lo), 0x07060302u);
}
// unpack truncated-bf16 lanes of a pk'd u32 back to f32 (for the loss diff)
__device__ __forceinline__ float xf0(unsigned u) { return __uint_as_float(u << 16); }
__device__ __forceinline__ float xf1(unsigned u) { return __uint_as_float(u & 0xFFFF0000u); }

// 16x16x16 bf16 MFMA: k-index = quad*4+e matches C-layout row = quad*4+r,
// so one stage's accumulator (relu+pk'd) IS the next stage's B-fragment.
__device__ __forceinline__ v4f mfma16(v4s a, v4s b, v4f c) {
  return __builtin_amdgcn_mfma_f32_16x16x16bf16_1k(a, b, c, 0, 0, 0);
}
__device__ __forceinline__ v4s lo4(v8s v) { return __builtin_shufflevector(v, v, 0, 1, 2, 3); }
__device__ __forceinline__ v4s hi4(v8s v) { return __builtin_shufflevector(v, v, 4, 5, 6, 7); }

__device__ __forceinline__ v4s rlpk(v4f h) {   // relu + pack to bf16 chunk
  u2v4 c;
  c.u[0] = pk(fmaxf(h[1], 0.f), fmaxf(h[0], 0.f));
  c.u[1] = pk(fmaxf(h[3], 0.f), fmaxf(h[2], 0.f));
  return c.s;
}
__device__ __forceinline__ v4s zpk(v4f z) {    // pack to bf16 chunk
  u2v4 c; c.u[0] = pk(z[1], z[0]); c.u[1] = pk(z[3], z[2]); return c.s;
}
__device__ __forceinline__ v4s mkv(unsigned a, unsigned b) {
  u2v4 c; c.u[0] = a; c.u[1] = b; return c.s;
}
// argmin key: dist upper bits | 9-bit code (float order == dist order to 2^-14 rel;
// lowest code wins ties among equal upper bits)
__device__ __forceinline__ float kpack(float d, unsigned code) {
  return __uint_as_float((__float_as_uint(d) & 0xFFFFFE00u) | code);
}
// swizzled in-row short offset for K-grouped tables: k = j*16 + q*4 + e
__device__ __forceinline__ int swz(int k, int Kq) {   // Kq = K/4
  return ((k >> 2) & 3) * Kq + (k >> 4) * 4 + (k & 3);
}

// ---- 2-tile stage 1+2 (b1 folded into lw1 @k=28; seed = 0) ----
__device__ __forceinline__ void s12_pair(
    const unsigned short* __restrict__ L, const float* __restrict__ LF,
    int lm, int quad,
    v4s bxa_lo, v4s bxa_hi, v4s bxb_lo, v4s bxb_hi,
    v4s& zfa0, v4s& zfa1, v4s& zfa2, v4s& zfa3,
    v4s& zfb0, v4s& zfb1, v4s& zfb2, v4s& zfb3,
    float& z2a, float& z2b) {
  const int fw1 = O_LW1 + lm * S1 + quad * 8;
  const int fw2 = O_LW2 + lm * S2 + quad * 32;
  v4f za[4], zb[4];
#pragma unroll
  for (int nt = 0; nt < 4; ++nt) {
    v4f s = *(const v4f*)&LF[512 + nt * 16 + quad * 4];      // b2 seed (broadcast)
    za[nt] = s; zb[nt] = s;
  }
#pragma unroll 1
  for (int jp = 0; jp < 4; ++jp) {
    v4s hA0, hA1, hB0, hB1;
    {
      v8s w = *(const v8s*)&L[fw1 + (2 * jp) * (16 * S1)];
      v4f zero = {0.f, 0.f, 0.f, 0.f};                       // b1 folded at k=28
      v4f h = mfma16(lo4(w), bxa_lo, zero);
      h = mfma16(hi4(w), bxa_hi, h);
      hA0 = rlpk(h);
      h = mfma16(lo4(w), bxb_lo, zero);
      h = mfma16(hi4(w), bxb_hi, h);
      hB0 = rlpk(h);
    }
    {
      v8s w = *(const v8s*)&L[fw1 + (2 * jp + 1) * (16 * S1)];
      v4f zero = {0.f, 0.f, 0.f, 0.f};
      v4f h = mfma16(lo4(w), bxa_lo, zero);
      h = mfma16(hi4(w), bxa_hi, h);
      hA1 = rlpk(h);
      h = mfma16(lo4(w), bxb_lo, zero);
      h = mfma16(hi4(w), bxb_hi, h);
      hB1 = rlpk(h);
    }
#pragma unroll
    for (int nt = 0; nt < 4; ++nt) {
      v8s w2 = *(const v8s*)&L[fw2 + nt * (16 * S2) + jp * 8];
      za[nt] = mfma16(lo4(w2), hA0, za[nt]);
      za[nt] = mfma16(hi4(w2), hA1, za[nt]);
      zb[nt] = mfma16(lo4(w2), hB0, zb[nt]);
      zb[nt] = mfma16(hi4(w2), hB1, zb[nt]);
    }
  }
  z2a = za[0][0] * za[0][0] + za[0][1] * za[0][1] + za[0][2] * za[0][2] + za[0][3] * za[0][3]
      + za[1][0] * za[1][0] + za[1][1] * za[1][1] + za[1][2] * za[1][2] + za[1][3] * za[1][3]
      + za[2][0] * za[2][0] + za[2][1] * za[2][1] + za[2][2] * za[2][2] + za[2][3] * za[2][3]
      + za[3][0] * za[3][0] + za[3][1] * za[3][1] + za[3][2] * za[3][2] + za[3][3] * za[3][3];
  z2b = zb[0][0] * zb[0][0] + zb[0][1] * zb[0][1] + zb[0][2] * zb[0][2] + zb[0][3] * zb[0][3]
      + zb[1][0] * zb[1][0] + zb[1][1] * zb[1][1] + zb[1][2] * zb[1][2] + zb[1][3] * zb[1][3]
      + zb[2][0] * zb[2][0] + zb[2][1] * zb[2][1] + zb[2][2] * zb[2][2] + zb[2][3] * zb[2][3]
      + zb[3][0] * zb[3][0] + zb[3][1] * zb[3][1] + zb[3][2] * zb[3][2] + zb[3][3] * zb[3][3];
  zfa0 = zpk(za[0]); zfa1 = zpk(za[1]); zfa2 = zpk(za[2]); zfa3 = zpk(za[3]);
  zfb0 = zpk(zb[0]); zfb1 = zpk(zb[1]); zfb2 = zpk(zb[2]); zfb3 = zpk(zb[3]);
}

// ---- 2-tile stage 5+6 (stores + loss; x from bf16 packs; quad3 hi = marker) ----
__device__ __forceinline__ void s56_pair(
    const unsigned short* __restrict__ L, const float* __restrict__ LF,
    int lm, int quad, int codeA, int codeB,
    unsigned xa0, unsigned xa1, unsigned xa2, unsigned xa3,
    unsigned xb0, unsigned xb1, unsigned xb2, unsigned xb3,
    float* __restrict__ orowA, float* __restrict__ orowB, float& racc) {
  const int fd1 = O_LD1 + lm * SC + quad * 16;
  const int fd2 = O_LD2 + lm * S2 + quad * 32;
  const int gA = O_LCB + codeA * SC + quad * 16;   // -2q rows (wave-uniform code)
  const int gB = O_LCB + codeB * SC + quad * 16;
  v8s qa0 = *(const v8s*)&L[gA];
  v8s qa1 = *(const v8s*)&L[gA + 8];
  v8s qb0 = *(const v8s*)&L[gB];
  v8s qb1 = *(const v8s*)&L[gB + 8];
  v4f a6a[2], a6b[2];
#pragma unroll
  for (int nt = 0; nt < 2; ++nt) {
    v4f s = *(const v4f*)&LF[704 + nt * 16 + quad * 4];      // db2 seed
    a6a[nt] = s; a6b[nt] = s;
  }
#pragma unroll 1
  for (int jp = 0; jp < 4; ++jp) {
    v4s hA0, hA1, hB0, hB1;
#pragma unroll
    for (int jj = 0; jj < 2; ++jj) {
      int j = 2 * jp + jj;
      v8s d0 = *(const v8s*)&L[fd1 + j * (16 * SC)];
      v8s d1 = *(const v8s*)&L[fd1 + j * (16 * SC) + 8];
      v4f sd = *(const v4f*)&LF[576 + j * 16 + quad * 4];    // db1 seed
      v4f h = mfma16(lo4(d0), lo4(qa0), sd);
      h = mfma16(hi4(d0), hi4(qa0), h);
      h = mfma16(lo4(d1), lo4(qa1), h);
      h = mfma16(hi4(d1), hi4(qa1), h);
      v4s ha = rlpk(h);
      h = mfma16(lo4(d0), lo4(qb0), sd);
      h = mfma16(hi4(d0), hi4(qb0), h);
      h = mfma16(lo4(d1), lo4(qb1), h);
      h = mfma16(hi4(d1), hi4(qb1), h);
      v4s hb = rlpk(h);
      if (jj == 0) { hA0 = ha; hB0 = hb; } else { hA1 = ha; hB1 = hb; }
    }
#pragma unroll
    for (int nt = 0; nt < 2; ++nt) {
      v8s w6 = *(const v8s*)&L[fd2 + nt * (16 * S2) + jp * 8];
      a6a[nt] = mfma16(lo4(w6), hA0, a6a[nt]);
      a6a[nt] = mfma16(hi4(w6), hA1, a6a[nt]);
      a6b[nt] = mfma16(lo4(w6), hB0, a6b[nt]);
      a6b[nt] = mfma16(hi4(w6), hB1, a6b[nt]);
    }
  }
  *(float4*)(orowA + quad * 4) = (float4){a6a[0][0], a6a[0][1], a6a[0][2], a6a[0][3]};
  *(float4*)(orowB + quad * 4) = (float4){a6b[0][0], a6b[0][1], a6b[0][2], a6b[0][3]};
  if (quad < 3) {
    *(float4*)(orowA + 16 + quad * 4) = (float4){a6a[1][0], a6a[1][1], a6a[1][2], a6a[1][3]};
    *(float4*)(orowB + 16 + quad * 4) = (float4){a6b[1][0], a6b[1][1], a6b[1][2], a6b[1][3]};
  }
  float d;
  d = a6a[0][0] - xf0(xa0); racc += d * d;
  d = a6a[0][1] - xf1(xa0); racc += d * d;
  d = a6a[0][2] - xf0(xa1); racc += d * d;
  d = a6a[0][3] - xf1(xa1); racc += d * d;
  d = a6b[0][0] - xf0(xb0); racc += d * d;
  d = a6b[0][1] - xf1(xb0); racc += d * d;
  d = a6b[0][2] - xf0(xb1); racc += d * d;
  d = a6b[0][3] - xf1(xb1); racc += d * d;
  if (quad < 3) {   // quad3 hi-pack holds the 1.0 bias marker, dims 28..31 don't exist
    d = a6a[1][0] - xf0(xa2); racc += d * d;
    d = a6a[1][1] - xf1(xa2); racc += d * d;
    d = a6a[1][2] - xf0(xa3); racc += d * d;
    d = a6a[1][3] - xf1(xa3); racc += d * d;
    d = a6b[1][0] - xf0(xb2); racc += d * d;
    d = a6b[1][1] - xf1(xb2); racc += d * d;
    d = a6b[1][2] - xf0(xb3); racc += d * d;
    d = a6b[1][3] - xf1(xb3); racc += d * d;
  }
}

// ---------------- single fused kernel ----------------
// Round-15: collapse the 3-kernel graph. Across r9-r14 the bench total exceeded
// vq_main by a stable 82-90 us; the only controllable theory is multi-kernel
// launch/drain overhead. Now ONE kernel (+4B memset node):
//  * prep in-kernel: each block builds its LDS tables from raw weights with
//    COALESCED loads (source-order loop, swizzled ds_write_b16 scatter) after a
//    float4 zero-fill. No blob workspace, no prep kernel.
//  * fin in-kernel: block reduce -> partials[256], device-scope atomic counter,
//    last block reduces 512 floats and writes the 2 scalars (fixed order =
//    deterministic). Counter zeroed by a captured hipMemsetAsync.
//  * b1 folded into lw1 at k=28 (x quad3-hi carries bf16(1.0)); loss hi-terms
//    guarded quad<3.
__global__ __attribute__((amdgpu_flat_work_group_size(1024, 1024)))
__attribute__((amdgpu_waves_per_eu(4, 4)))
void vq_main(
    const float* __restrict__ x,
    const float* __restrict__ ew1, const float* __restrict__ eb1,
    const float* __restrict__ ew2, const float* __restrict__ eb2,
    const float* __restrict__ cb,  const float* __restrict__ dw1,
    const float* __restrict__ db1, const float* __restrict__ dw2,
    const float* __restrict__ db2,
    float* __restrict__ out, float* __restrict__ partials,
    unsigned* __restrict__ counter) {

  extern __shared__ __align__(16) char smem[];
  unsigned short* Lw = (unsigned short*)smem;
  const unsigned short* L = (const unsigned short*)smem;
  float* fbw = (float*)(smem + BLOB_SHORTS * 2);
  const float* LF = (const float*)(smem + BLOB_SHORTS * 2);

  const int tid  = threadIdx.x;
  const int wave = tid >> 6;
  const int lane = tid & 63;
  const int quad = lane >> 4;
  const int lm   = lane & 15;

  // ==== in-block prep: zero shorts region, then fill (coalesced src reads) ====
  {
    float4* z4 = (float4*)smem;
    float4 z = {0.f, 0.f, 0.f, 0.f};
#pragma unroll
    for (int it = 0; it < 8; ++it) {
      int idx = it * 1024 + tid;
      if (idx < BLOB_SHORTS / 8) z4[idx] = z;
    }
  }
  __syncthreads();
  {
    // lw1 <- ew1 [28][128]
    for (int t = tid; t < IN_DIM * HID; t += 1024) {
      int k = t >> 7, row = t & 127;
      Lw[O_LW1 + row * S1 + swz(k, 8)] = f2bf(ew1[t]);
    }
    if (tid < HID)                       // b1 fold at k=28 -> off 28
      Lw[O_LW1 + tid * S1 + 28] = f2bf(eb1[tid]);
    // lw2 <- ew2 [128][64]
    for (int t = tid; t < HID * LAT; t += 1024) {
      int k = t >> 6, row = t & 63;
      Lw[O_LW2 + row * S2 + swz(k, 32)] = f2bf(ew2[t]);
    }
    // lcb <- -2*cb [512][64]
    for (int t = tid; t < NCODES * LAT; t += 1024) {
      int c = t >> 6, d = t & 63;
      Lw[O_LCB + c * SC + swz(d, 16)] = f2bf(-2.0f * cb[t]);
    }
    // ld1 <- -0.5*dw1 [64][128]
    for (int t = tid; t < LAT * HID; t += 1024) {
      int k = t >> 7, row = t & 127;
      Lw[O_LD1 + row * SC + swz(k, 16)] = f2bf(-0.5f * dw1[t]);
    }
    // ld2 <- dw2 [128][28]
    for (int t = tid; t < HID * IN_DIM; t += 1024) {
      int k = t / IN_DIM, n = t - k * IN_DIM;
      Lw[O_LD2 + n * S2 + swz(k, 32)] = f2bf(dw2[t]);
    }
    // e2: 8 lanes per code, float4 loads
    for (int t = tid; t < NCODES * 8; t += 1024) {
      int c = t >> 3, l = t & 7;
      const float* p = cb + c * LAT + l * 8;
      float4 a = *(const float4*)p;
      float4 b = *(const float4*)(p + 4);
      float s = a.x * a.x + a.y * a.y + a.z * a.z + a.w * a.w
              + b.x * b.x + b.y * b.y + b.z * b.z + b.w * b.w;
      s += __shfl_xor(s, 1, 64);
      s += __shfl_xor(s, 2, 64);
      s += __shfl_xor(s, 4, 64);
      if (l == 0) fbw[c] = s;
    }
    if (tid < 64)  fbw[512 + tid] = eb2[tid];
    if (tid < 128) fbw[576 + tid] = db1[tid];
    if (tid < 32)  fbw[704 + tid] = (tid < IN_DIM) ? db2[tid] : 0.f;
  }
  __syncthreads();

  // ==== main compute (r14 structure) ====
  const int rbase = blockIdx.x * 1024 + wave * 64;
  float racc = 0.f, vqacc = 0.f;

#pragma unroll 1
  for (int sw = 0; sw < 2; ++sw) {
    const int r0 = rbase + sw * 32;

    unsigned xa0, xa1, xa2, xa3, xb0, xb1, xb2, xb3;
    {
      const float* xpa = x + (size_t)(r0 + lm) * IN_DIM;
      const float* xpb = x + (size_t)(r0 + 16 + lm) * IN_DIM;
      float4 t = *(const float4*)(xpa + quad * 4);
      xa0 = pk(t.y, t.x); xa1 = pk(t.w, t.z);
      t = (quad < 3) ? *(const float4*)(xpa + 16 + quad * 4)
                     : (float4){1.f, 0.f, 0.f, 0.f};          // k=28 bias marker
      xa2 = pk(t.y, t.x); xa3 = pk(t.w, t.z);
      t = *(const float4*)(xpb + quad * 4);
      xb0 = pk(t.y, t.x); xb1 = pk(t.w, t.z);
      t = (quad < 3) ? *(const float4*)(xpb + 16 + quad * 4)
                     : (float4){1.f, 0.f, 0.f, 0.f};
      xb2 = pk(t.y, t.x); xb3 = pk(t.w, t.z);
    }

    v4s zfa0, zfa1, zfa2, zfa3, zfb0, zfb1, zfb2, zfb3;
    float z2a, z2b;
    s12_pair(L, LF, lm, quad,
             mkv(xa0, xa1), mkv(xa2, xa3), mkv(xb0, xb1), mkv(xb2, xb3),
             zfa0, zfa1, zfa2, zfa3, zfb0, zfb1, zfb2, zfb3, z2a, z2b);
    __builtin_amdgcn_sched_barrier(0);

    const int fcb = O_LCB + lm * SC + quad * 16;
    float bkA = __uint_as_float(0x7f7fffffu);
    float bkB = bkA;
#pragma unroll 2
    for (int ct = 0; ct < 32; ++ct) {
      v8s c0 = *(const v8s*)&L[fcb + ct * (16 * SC)];
      v8s c1 = *(const v8s*)&L[fcb + ct * (16 * SC) + 8];
      v4f sd = *(const v4f*)&LF[ct * 16 + quad * 4];         // e2 seed
      v4f dA = mfma16(lo4(c0), zfa0, sd);
      dA = mfma16(hi4(c0), zfa1, dA);
      dA = mfma16(lo4(c1), zfa2, dA);
      dA = mfma16(hi4(c1), zfa3, dA);
      v4f dB = mfma16(lo4(c0), zfb0, sd);
      dB = mfma16(hi4(c0), zfb1, dB);
      dB = mfma16(lo4(c1), zfb2, dB);
      dB = mfma16(hi4(c1), zfb3, dB);
      unsigned cbase = (unsigned)(ct * 16 + quad * 4);
      bkA = fminf(bkA, fminf(fminf(kpack(dA[0], cbase), kpack(dA[1], cbase + 1)),
                             fminf(kpack(dA[2], cbase + 2), kpack(dA[3], cbase + 3))));
      bkB = fminf(bkB, fminf(fminf(kpack(dB[0], cbase), kpack(dB[1], cbase + 1)),
                             fminf(kpack(dB[2], cbase + 2), kpack(dB[3], cbase + 3))));
    }

#pragma unroll
    for (int off = 16; off < 64; off <<= 1) {
      bkA = fminf(bkA, __shfl_xor(bkA, off, 64));
      bkB = fminf(bkB, __shfl_xor(bkB, off, 64));
      z2a += __shfl_xor(z2a, off, 64);
      z2b += __shfl_xor(z2b, off, 64);
    }
    unsigned ka = __float_as_uint(bkA), kb = __float_as_uint(bkB);
    int codeA = (int)(ka & 511u), codeB = (int)(kb & 511u);
    if (quad == 0)
      vqacc += z2a + __uint_as_float(ka & 0xFFFFFE00u)
             + z2b + __uint_as_float(kb & 0xFFFFFE00u);      // ||z-q||^2
    __builtin_amdgcn_sched_barrier(0);

    s56_pair(L, LF, lm, quad, codeA, codeB,
             xa0, xa1, xa2, xa3, xb0, xb1, xb2, xb3,
             out + (size_t)(r0 + lm) * IN_DIM,
             out + (size_t)(r0 + 16 + lm) * IN_DIM, racc);
    __builtin_amdgcn_sched_barrier(0);
  }

  // ==== per-wave -> per-block reduce, completion counter, in-kernel finalize ====
#pragma unroll
  for (int off = 1; off < 64; off <<= 1) {
    racc  += __shfl_xor(racc, off, 64);
    vqacc += __shfl_xor(vqacc, off, 64);
  }
  __syncthreads();                       // all table reads done; smem reusable
  float* sc = (float*)smem;
  if (lane == 0) { sc[wave * 2] = racc; sc[wave * 2 + 1] = vqacc; }
  __syncthreads();
  int* flag = (int*)(smem + 256);
  if (tid == 0) {
    float R = 0.f, V = 0.f;
#pragma unroll
    for (int w = 0; w < WVS; ++w) { R += sc[2 * w]; V += sc[2 * w + 1]; }
    partials[blockIdx.x * 2]     = R;
    partials[blockIdx.x * 2 + 1] = V;
    __threadfence();                     // release partials device-wide
    unsigned t = atomicAdd(counter, 1u);
    *flag = (t == NBLK - 1) ? 1 : 0;
  }
  __syncthreads();
  if (*flag) {                           // last block finalizes
    __threadfence();
    float r = 0.f, v = 0.f;
    if (tid < NBLK) { r = partials[2 * tid]; v = partials[2 * tid + 1]; }
#pragma unroll
    for (int off = 1; off < 64; off <<= 1) {
      r += __shfl_xor(r, off, 64);
      v += __shfl_xor(v, off, 64);
    }
    if (lane == 0) { sc[64 + wave * 2] = r; sc[64 + wave * 2 + 1] = v; }
    __syncthreads();
    if (tid == 0) {
      float R = 0.f, V = 0.f;
#pragma unroll
      for (int w = 0; w < 4; ++w) { R += sc[64 + 2 * w]; V += sc[64 + 2 * w + 1]; }
      out[7340032] = R * (1.0f / 7340032.0f);        // recon_loss = S / (B*28)
      out[7340033] = V * (1.25f / 16777216.0f);      // vq_loss = 1.25 * S / (B*64)
    }
  }
}

extern "C" void kernel_launch(void* const* d_in, const int* in_sizes, int n_in,
                              void* d_out, int out_size, void* d_ws, size_t ws_size,
                              hipStream_t stream) {
  const float* x   = (const float*)d_in[0];
  const float* ew1 = (const float*)d_in[1];
  const float* eb1 = (const float*)d_in[2];
  const float* ew2 = (const float*)d_in[3];
  const float* eb2 = (const float*)d_in[4];
  const float* cb  = (const float*)d_in[5];
  const float* dw1 = (const float*)d_in[6];
  const float* db1 = (const float*)d_in[7];
  const float* dw2 = (const float*)d_in[8];
  const float* db2 = (const float*)d_in[9];

  char* ws = (char*)d_ws;
  float* partials = (float*)ws;                       // 256*2 f32 = 2048 B
  unsigned* counter = (unsigned*)(ws + 2048);         // 4 B

  float* out = (float*)d_out;

  // allow >64 KB dynamic LDS (gfx950 workgroup max is 160 KB)
  (void)hipFuncSetAttribute((const void*)vq_main,
                            hipFuncAttributeMaxDynamicSharedMemorySize, LDS_BYTES);

  (void)hipMemsetAsync(counter, 0, 4, stream);        // graph node: re-zeroed每replay
  vq_main<<<NBLK, 1024, LDS_BYTES, stream>>>(
      x, ew1, eb1, ew2, eb2, cb, dw1, db1, dw2, db2, out, partials, counter);
}

// Round 7
// 139.849 us; speedup vs baseline: 1.0305x; 1.0305x over previous
//
#include <hip/hip_runtime.h>

#define BATCH   262144
#define IN_DIM  28
#define HID     128
#define LAT     64
#define NCODES  512
#define NBLK    256             // 1024 rows per block (16 waves x 64 rows)
#define WVS     16

// ---- quad-grouped LDS table geometry ----
// Element (row,k) stored at row*S + q'*(K/4) + j*4 + e where k = j*16 + q'*4 + e.
// A lane (lm, quad) reading its mfma16 A-frags reads K/4 CONTIGUOUS shorts at
// row*S + quad*(K/4): pure ds_read_b128, 16B-aligned. Strides 40/72/136 shorts
// (80/144/272 B) give 2-way bank aliasing only on the b128 READ path (free).
#define S1 40     // lw1  [128][40]  K=32  (k>=28 zero)
#define S2 136    // lw2/ld2 [..][136] K=128
#define SC 72     // lcb/ld1 [..][72]  K=64
#define O_LW1 0
#define O_LW2 5120
#define O_LCB 13824
#define O_LD1 50688
#define O_LD2 59904
#define BLOB_SHORTS 64256
#define BLOB_F32    864
#define BLOB_BYTES  (BLOB_SHORTS * 2 + BLOB_F32 * 4)   // 131968
#define LDS_BYTES   BLOB_BYTES

// prep thread-index regions (e2 is 8-lane-parallel)
#define E2_BASE   BLOB_SHORTS            // 4096 threads (8 per code)
#define B1_BASE   (BLOB_SHORTS + 4096)
#define B2_BASE   (B1_BASE + 128)
#define DB1_BASE  (B2_BASE + 64)
#define DB2_BASE  (DB1_BASE + 128)
#define PREP_END  (DB2_BASE + 32)

typedef short v4s __attribute__((ext_vector_type(4)));
typedef short v8s __attribute__((ext_vector_type(8)));
typedef float v4f __attribute__((ext_vector_type(4)));

union u2v4 { unsigned u[2]; v4s s; };

__device__ __forceinline__ unsigned short f2bf(float f) {   // RNE (prep only)
  unsigned u = __float_as_uint(f);
  u += 0x7fffu + ((u >> 16) & 1u);
  return (unsigned short)(u >> 16);
}
// pack two truncated bf16 (hi, lo) in ONE v_perm_b32 (truncation validated r7/r8)
__device__ __forceinline__ unsigned pk(float hi, float lo) {
  return __builtin_amdgcn_perm(__float_as_uint(hi), __float_as_uint(lo), 0x07060302u);
}
// unpack truncated-bf16 lanes of a pk'd u32 back to f32 (for the loss diff)
__device__ __forceinline__ float xf0(unsigned u) { return __uint_as_float(u << 16); }
__device__ __forceinline__ float xf1(unsigned u) { return __uint_as_float(u & 0xFFFF0000u); }

// 16x16x16 bf16 MFMA: k-index = quad*4+e matches C-layout row = quad*4+r,
// so one stage's accumulator (relu+pk'd) IS the next stage's B-fragment.
__device__ __forceinline__ v4f mfma16(v4s a, v4s b, v4f c) {
  return __builtin_amdgcn_mfma_f32_16x16x16bf16_1k(a, b, c, 0, 0, 0);
}
__device__ __forceinline__ v4s lo4(v8s v) { return __builtin_shufflevector(v, v, 0, 1, 2, 3); }
__device__ __forceinline__ v4s hi4(v8s v) { return __builtin_shufflevector(v, v, 4, 5, 6, 7); }

__device__ __forceinline__ v4s rlpk(v4f h) {   // relu + pack to bf16 chunk
  u2v4 c;
  c.u[0] = pk(fmaxf(h[1], 0.f), fmaxf(h[0], 0.f));
  c.u[1] = pk(fmaxf(h[3], 0.f), fmaxf(h[2], 0.f));
  return c.s;
}
__device__ __forceinline__ v4s zpk(v4f z) {    // pack to bf16 chunk
  u2v4 c; c.u[0] = pk(z[1], z[0]); c.u[1] = pk(z[3], z[2]); return c.s;
}
__device__ __forceinline__ v4s mkv(unsigned a, unsigned b) {
  u2v4 c; c.u[0] = a; c.u[1] = b; return c.s;
}
// argmin key: dist upper bits | 9-bit code (float order == dist order to 2^-14 rel;
// lowest code wins ties among equal upper bits)
__device__ __forceinline__ float kpack(float d, unsigned code) {
  return __uint_as_float((__float_as_uint(d) & 0xFFFFFE00u) | code);
}

// Blob layout (short offsets), quad-grouped, pad zeroed:
//   lw1 @0      [128 hid][40]   enc_w1^T   (K=32 slot, k>=28 zero)
//   lw2 @5120   [64  lat][136]  enc_w2^T   (K=128)
//   lcb @13824  [512 code][72]  bf16(-2*codebook) (K=64)
//   ld1 @50688  [128 hid][72]   bf16(-0.5*dec_w1^T)  (scale cancels -2q)
//   ld2 @59904  [32  n][136]    dec_w2^T   (rows n>=28 zero)
// f32 @ byte 128512: e2[512], b1[128], b2[64], db1[128], db2[32 pad0]
__global__ __launch_bounds__(256) void vq_prep(
    const float* __restrict__ ew1, const float* __restrict__ eb1,
    const float* __restrict__ ew2, const float* __restrict__ eb2,
    const float* __restrict__ cb,  const float* __restrict__ dw1,
    const float* __restrict__ db1, const float* __restrict__ dw2,
    const float* __restrict__ db2,
    unsigned short* __restrict__ blob) {
  int i = blockIdx.x * 256 + threadIdx.x;
  float* fb = (float*)(blob + BLOB_SHORTS);
  if (i < O_LW2) {                       // lw1 [128][40] K=32 per=8
    int row = i / S1, s = i % S1;
    unsigned short v = 0;
    if (s < 32) {
      int q = s >> 3, r2 = s & 7, j = r2 >> 2, e = r2 & 3;
      int k = j * 16 + q * 4 + e;
      if (k < IN_DIM) v = f2bf(ew1[k * HID + row]);
    }
    blob[i] = v;
  } else if (i < O_LCB) {                // lw2 [64][136] K=128 per=32
    int j2 = i - O_LW2; int row = j2 / S2, s = j2 % S2;
    unsigned short v = 0;
    if (s < 128) {
      int q = s >> 5, r2 = s & 31, j = r2 >> 2, e = r2 & 3;
      int k = j * 16 + q * 4 + e;
      v = f2bf(ew2[k * LAT + row]);
    }
    blob[i] = v;
  } else if (i < O_LD1) {                // lcb [512][72] K=64 per=16, = -2*cb
    int j2 = i - O_LCB; int row = j2 / SC, s = j2 % SC;
    unsigned short v = 0;
    if (s < 64) {
      int q = s >> 4, r2 = s & 15, j = r2 >> 2, e = r2 & 3;
      int k = j * 16 + q * 4 + e;
      v = f2bf(-2.0f * cb[row * LAT + k]);
    }
    blob[i] = v;
  } else if (i < O_LD2) {                // ld1 [128][72] = -0.5*dec_w1^T
    int j2 = i - O_LD1; int row = j2 / SC, s = j2 % SC;
    unsigned short v = 0;
    if (s < 64) {
      int q = s >> 4, r2 = s & 15, j = r2 >> 2, e = r2 & 3;
      int k = j * 16 + q * 4 + e;
      v = f2bf(-0.5f * dw1[k * HID + row]);
    }
    blob[i] = v;
  } else if (i < BLOB_SHORTS) {          // ld2 [32][136]
    int j2 = i - O_LD2; int row = j2 / S2, s = j2 % S2;
    unsigned short v = 0;
    if (s < 128 && row < IN_DIM) {
      int q = s >> 5, r2 = s & 31, j = r2 >> 2, e = r2 & 3;
      int k = j * 16 + q * 4 + e;
      v = f2bf(dw2[k * IN_DIM + row]);
    }
    blob[i] = v;
  } else if (i < B1_BASE) {              // e2: 8 lanes per code, float4 loads
    int j = i - E2_BASE;                 // wave-aligned region
    int c = j >> 3, l = j & 7;
    const float* p = cb + c * LAT + l * 8;
    float4 a = *(const float4*)p;
    float4 b = *(const float4*)(p + 4);
    float s = a.x * a.x + a.y * a.y + a.z * a.z + a.w * a.w
            + b.x * b.x + b.y * b.y + b.z * b.z + b.w * b.w;
    s += __shfl_xor(s, 1, 64);
    s += __shfl_xor(s, 2, 64);
    s += __shfl_xor(s, 4, 64);
    if (l == 0) fb[c] = s;
  } else if (i < B2_BASE) {
    fb[512 + (i - B1_BASE)] = eb1[i - B1_BASE];
  } else if (i < DB1_BASE) {
    fb[640 + (i - B2_BASE)] = eb2[i - B2_BASE];
  } else if (i < DB2_BASE) {
    fb[704 + (i - DB1_BASE)] = db1[i - DB1_BASE];
  } else if (i < PREP_END) {
    int k = i - DB2_BASE;
    fb[832 + k] = (k < IN_DIM) ? db2[k] : 0.f;
  }
}

// ---- 2-tile stage 1+2: x -> h -> z for tiles A and B, every weight fragment
// read ONCE and consumed by both tiles. jp-loop stays #pragma unroll 1: the
// back-edge caps scheduler load-hoisting (~6 v8s in flight) -> spill-free.
__device__ __forceinline__ void s12_pair(
    const unsigned short* __restrict__ L, const float* __restrict__ LF,
    int lm, int quad,
    v4s bxa_lo, v4s bxa_hi, v4s bxb_lo, v4s bxb_hi,
    v4s& zfa0, v4s& zfa1, v4s& zfa2, v4s& zfa3,
    v4s& zfb0, v4s& zfb1, v4s& zfb2, v4s& zfb3,
    float& z2a, float& z2b) {
  const int fw1 = O_LW1 + lm * S1 + quad * 8;
  const int fw2 = O_LW2 + lm * S2 + quad * 32;
  v4f za[4], zb[4];
#pragma unroll
  for (int nt = 0; nt < 4; ++nt) {
    v4f s = *(const v4f*)&LF[640 + nt * 16 + quad * 4];      // b2 seed (broadcast)
    za[nt] = s; zb[nt] = s;
  }
#pragma unroll 1
  for (int jp = 0; jp < 4; ++jp) {
    v4s hA0, hA1, hB0, hB1;
    {
      v8s w = *(const v8s*)&L[fw1 + (2 * jp) * (16 * S1)];
      v4f sd = *(const v4f*)&LF[512 + (2 * jp) * 16 + quad * 4];   // b1 seed
      v4f h = mfma16(lo4(w), bxa_lo, sd);
      h = mfma16(hi4(w), bxa_hi, h);
      hA0 = rlpk(h);
      h = mfma16(lo4(w), bxb_lo, sd);
      h = mfma16(hi4(w), bxb_hi, h);
      hB0 = rlpk(h);
    }
    {
      v8s w = *(const v8s*)&L[fw1 + (2 * jp + 1) * (16 * S1)];
      v4f sd = *(const v4f*)&LF[512 + (2 * jp + 1) * 16 + quad * 4];
      v4f h = mfma16(lo4(w), bxa_lo, sd);
      h = mfma16(hi4(w), bxa_hi, h);
      hA1 = rlpk(h);
      h = mfma16(lo4(w), bxb_lo, sd);
      h = mfma16(hi4(w), bxb_hi, h);
      hB1 = rlpk(h);
    }
#pragma unroll
    for (int nt = 0; nt < 4; ++nt) {
      v8s w2 = *(const v8s*)&L[fw2 + nt * (16 * S2) + jp * 8];
      za[nt] = mfma16(lo4(w2), hA0, za[nt]);
      za[nt] = mfma16(hi4(w2), hA1, za[nt]);
      zb[nt] = mfma16(lo4(w2), hB0, zb[nt]);
      zb[nt] = mfma16(hi4(w2), hB1, zb[nt]);
    }
  }
  z2a = za[0][0] * za[0][0] + za[0][1] * za[0][1] + za[0][2] * za[0][2] + za[0][3] * za[0][3]
      + za[1][0] * za[1][0] + za[1][1] * za[1][1] + za[1][2] * za[1][2] + za[1][3] * za[1][3]
      + za[2][0] * za[2][0] + za[2][1] * za[2][1] + za[2][2] * za[2][2] + za[2][3] * za[2][3]
      + za[3][0] * za[3][0] + za[3][1] * za[3][1] + za[3][2] * za[3][2] + za[3][3] * za[3][3];
  z2b = zb[0][0] * zb[0][0] + zb[0][1] * zb[0][1] + zb[0][2] * zb[0][2] + zb[0][3] * zb[0][3]
      + zb[1][0] * zb[1][0] + zb[1][1] * zb[1][1] + zb[1][2] * zb[1][2] + zb[1][3] * zb[1][3]
      + zb[2][0] * zb[2][0] + zb[2][1] * zb[2][1] + zb[2][2] * zb[2][2] + zb[2][3] * zb[2][3]
      + zb[3][0] * zb[3][0] + zb[3][1] * zb[3][1] + zb[3][2] * zb[3][2] + zb[3][3] * zb[3][3];
  zfa0 = zpk(za[0]); zfa1 = zpk(za[1]); zfa2 = zpk(za[2]); zfa3 = zpk(za[3]);
  zfb0 = zpk(zb[0]); zfb1 = zpk(zb[1]); zfb2 = zpk(zb[2]); zfb3 = zpk(zb[3]);
}

// ---- 2-tile stage 5+6: q -> hd -> recon for both tiles, weight fragments
// shared; includes stores + loss (x from bf16 packs).
__device__ __forceinline__ void s56_pair(
    const unsigned short* __restrict__ L, const float* __restrict__ LF,
    int lm, int quad, int codeA, int codeB,
    unsigned xa0, unsigned xa1, unsigned xa2, unsigned xa3,
    unsigned xb0, unsigned xb1, unsigned xb2, unsigned xb3,
    float* __restrict__ orowA, float* __restrict__ orowB, float& racc) {
  const int fd1 = O_LD1 + lm * SC + quad * 16;
  const int fd2 = O_LD2 + lm * S2 + quad * 32;
  const int gA = O_LCB + codeA * SC + quad * 16;   // -2q rows (wave-uniform code)
  const int gB = O_LCB + codeB * SC + quad * 16;
  v8s qa0 = *(const v8s*)&L[gA];
  v8s qa1 = *(const v8s*)&L[gA + 8];
  v8s qb0 = *(const v8s*)&L[gB];
  v8s qb1 = *(const v8s*)&L[gB + 8];
  v4f a6a[2], a6b[2];
#pragma unroll
  for (int nt = 0; nt < 2; ++nt) {
    v4f s = *(const v4f*)&LF[832 + nt * 16 + quad * 4];      // db2 seed
    a6a[nt] = s; a6b[nt] = s;
  }
#pragma unroll 1
  for (int jp = 0; jp < 4; ++jp) {
    v4s hA0, hA1, hB0, hB1;
#pragma unroll
    for (int jj = 0; jj < 2; ++jj) {
      int j = 2 * jp + jj;
      v8s d0 = *(const v8s*)&L[fd1 + j * (16 * SC)];
      v8s d1 = *(const v8s*)&L[fd1 + j * (16 * SC) + 8];
      v4f sd = *(const v4f*)&LF[704 + j * 16 + quad * 4];    // db1 seed
      v4f h = mfma16(lo4(d0), lo4(qa0), sd);
      h = mfma16(hi4(d0), hi4(qa0), h);
      h = mfma16(lo4(d1), lo4(qa1), h);
      h = mfma16(hi4(d1), hi4(qa1), h);
      v4s ha = rlpk(h);
      h = mfma16(lo4(d0), lo4(qb0), sd);
      h = mfma16(hi4(d0), hi4(qb0), h);
      h = mfma16(lo4(d1), lo4(qb1), h);
      h = mfma16(hi4(d1), hi4(qb1), h);
      v4s hb = rlpk(h);
      if (jj == 0) { hA0 = ha; hB0 = hb; } else { hA1 = ha; hB1 = hb; }
    }
#pragma unroll
    for (int nt = 0; nt < 2; ++nt) {
      v8s w6 = *(const v8s*)&L[fd2 + nt * (16 * S2) + jp * 8];
      a6a[nt] = mfma16(lo4(w6), hA0, a6a[nt]);
      a6a[nt] = mfma16(hi4(w6), hA1, a6a[nt]);
      a6b[nt] = mfma16(lo4(w6), hB0, a6b[nt]);
      a6b[nt] = mfma16(hi4(w6), hB1, a6b[nt]);
    }
  }
  *(float4*)(orowA + quad * 4) = (float4){a6a[0][0], a6a[0][1], a6a[0][2], a6a[0][3]};
  *(float4*)(orowB + quad * 4) = (float4){a6b[0][0], a6b[0][1], a6b[0][2], a6b[0][3]};
  if (quad < 3) {
    *(float4*)(orowA + 16 + quad * 4) = (float4){a6a[1][0], a6a[1][1], a6a[1][2], a6a[1][3]};
    *(float4*)(orowB + 16 + quad * 4) = (float4){a6b[1][0], a6b[1][1], a6b[1][2], a6b[1][3]};
  }
  float d;
  d = a6a[0][0] - xf0(xa0); racc += d * d;
  d = a6a[0][1] - xf1(xa0); racc += d * d;
  d = a6a[0][2] - xf0(xa1); racc += d * d;
  d = a6a[0][3] - xf1(xa1); racc += d * d;
  d = a6a[1][0] - xf0(xa2); racc += d * d;   // quad3: a6[1]==0 and x==0
  d = a6a[1][1] - xf1(xa2); racc += d * d;
  d = a6a[1][2] - xf0(xa3); racc += d * d;
  d = a6a[1][3] - xf1(xa3); racc += d * d;
  d = a6b[0][0] - xf0(xb0); racc += d * d;
  d = a6b[0][1] - xf1(xb0); racc += d * d;
  d = a6b[0][2] - xf0(xb1); racc += d * d;
  d = a6b[0][3] - xf1(xb1); racc += d * d;
  d = a6b[1][0] - xf0(xb2); racc += d * d;
  d = a6b[1][1] - xf1(xb2); racc += d * d;
  d = a6b[1][2] - xf0(xb3); racc += d * d;
  d = a6b[1][3] - xf1(xb3); racc += d * d;
}

// ---------------- fused main kernel ----------------
// Round-16: r15's single-kernel probe measured the harness-fixed overhead at
// ~74 us and showed per-block in-kernel prep costs ~+18 us of main (256x
// redundant scalar scatter, 8-way write conflicts). So: REVERT to r14's proven
// main (49.5 us) + split prep kernel, and keep only r15's profitable piece --
// the in-kernel finalize (per-block reduce -> 256 partials -> atomic counter ->
// last block writes the 2 scalars). Removes the vq_fin kernel + launch from
// the graph with zero main-loop change.
__global__ __attribute__((amdgpu_flat_work_group_size(1024, 1024)))
__attribute__((amdgpu_waves_per_eu(4, 4)))
void vq_main(
    const float* __restrict__ x,
    const unsigned short* __restrict__ blob,
    float* __restrict__ out, float* __restrict__ partials,
    unsigned* __restrict__ counter) {

  extern __shared__ __align__(16) char smem[];
  const unsigned short* L = (const unsigned short*)smem;
  const float*         LF = (const float*)(smem + BLOB_SHORTS * 2);

  const int tid  = threadIdx.x;
  const int wave = tid >> 6;
  const int lane = tid & 63;
  const int quad = lane >> 4;
  const int lm   = lane & 15;

  // ---- stage tables into LDS (one-time) ----
  {
    const float4* src = (const float4*)blob;
    float4* dst = (float4*)smem;
#pragma unroll
    for (int it = 0; it < 9; ++it) {
      int idx = it * 1024 + tid;
      if (idx < BLOB_BYTES / 16) dst[idx] = src[idx];
    }
  }
  __syncthreads();

  const int rbase = blockIdx.x * 1024 + wave * 64;
  float racc = 0.f, vqacc = 0.f;

#pragma unroll 1
  for (int sw = 0; sw < 2; ++sw) {
    const int r0 = rbase + sw * 32;

    // ---- x load -> packed bf16 only (f32 temps die immediately) ----
    unsigned xa0, xa1, xa2, xa3, xb0, xb1, xb2, xb3;
    {
      const float* xpa = x + (size_t)(r0 + lm) * IN_DIM;
      const float* xpb = x + (size_t)(r0 + 16 + lm) * IN_DIM;
      float4 t = *(const float4*)(xpa + quad * 4);
      xa0 = pk(t.y, t.x); xa1 = pk(t.w, t.z);
      t = (quad < 3) ? *(const float4*)(xpa + 16 + quad * 4) : (float4){0.f, 0.f, 0.f, 0.f};
      xa2 = pk(t.y, t.x); xa3 = pk(t.w, t.z);
      t = *(const float4*)(xpb + quad * 4);
      xb0 = pk(t.y, t.x); xb1 = pk(t.w, t.z);
      t = (quad < 3) ? *(const float4*)(xpb + 16 + quad * 4) : (float4){0.f, 0.f, 0.f, 0.f};
      xb2 = pk(t.y, t.x); xb3 = pk(t.w, t.z);
    }

    // ---- stages 1+2, tiles A+B together (fragments shared) ----
    v4s zfa0, zfa1, zfa2, zfa3, zfb0, zfb1, zfb2, zfb3;
    float z2a, z2b;
    s12_pair(L, LF, lm, quad,
             mkv(xa0, xa1), mkv(xa2, xa3), mkv(xb0, xb1), mkv(xb2, xb3),
             zfa0, zfa1, zfa2, zfa3, zfb0, zfb1, zfb2, zfb3, z2a, z2b);
    __builtin_amdgcn_sched_barrier(0);

    // ---- argmin: dist^T = e2 + (-2e)·z; cb fragments SHARED by both tiles ----
    const int fcb = O_LCB + lm * SC + quad * 16;
    float bkA = __uint_as_float(0x7f7fffffu);
    float bkB = bkA;
#pragma unroll 2
    for (int ct = 0; ct < 32; ++ct) {
      v8s c0 = *(const v8s*)&L[fcb + ct * (16 * SC)];        // chunks 0,1
      v8s c1 = *(const v8s*)&L[fcb + ct * (16 * SC) + 8];    // chunks 2,3
      v4f sd = *(const v4f*)&LF[ct * 16 + quad * 4];         // e2 seed
      v4f dA = mfma16(lo4(c0), zfa0, sd);
      dA = mfma16(hi4(c0), zfa1, dA);
      dA = mfma16(lo4(c1), zfa2, dA);
      dA = mfma16(hi4(c1), zfa3, dA);
      v4f dB = mfma16(lo4(c0), zfb0, sd);
      dB = mfma16(hi4(c0), zfb1, dB);
      dB = mfma16(lo4(c1), zfb2, dB);
      dB = mfma16(hi4(c1), zfb3, dB);
      unsigned cbase = (unsigned)(ct * 16 + quad * 4);
      bkA = fminf(bkA, fminf(fminf(kpack(dA[0], cbase), kpack(dA[1], cbase + 1)),
                             fminf(kpack(dA[2], cbase + 2), kpack(dA[3], cbase + 3))));
      bkB = fminf(bkB, fminf(fminf(kpack(dB[0], cbase), kpack(dB[1], cbase + 1)),
                             fminf(kpack(dB[2], cbase + 2), kpack(dB[3], cbase + 3))));
    }

    // ---- cross-quad argmin + z2 reduce ----
#pragma unroll
    for (int off = 16; off < 64; off <<= 1) {
      bkA = fminf(bkA, __shfl_xor(bkA, off, 64));
      bkB = fminf(bkB, __shfl_xor(bkB, off, 64));
      z2a += __shfl_xor(z2a, off, 64);
      z2b += __shfl_xor(z2b, off, 64);
    }
    unsigned ka = __float_as_uint(bkA), kb = __float_as_uint(bkB);
    int codeA = (int)(ka & 511u), codeB = (int)(kb & 511u);
    if (quad == 0)
      vqacc += z2a + __uint_as_float(ka & 0xFFFFFE00u)
             + z2b + __uint_as_float(kb & 0xFFFFFE00u);      // ||z-q||^2
    __builtin_amdgcn_sched_barrier(0);

    // ---- stages 5+6 + store + loss, tiles A+B together ----
    s56_pair(L, LF, lm, quad, codeA, codeB,
             xa0, xa1, xa2, xa3, xb0, xb1, xb2, xb3,
             out + (size_t)(r0 + lm) * IN_DIM,
             out + (size_t)(r0 + 16 + lm) * IN_DIM, racc);
    __builtin_amdgcn_sched_barrier(0);
  }

  // ==== per-wave -> per-block reduce -> device counter -> last-block finalize ====
#pragma unroll
  for (int off = 1; off < 64; off <<= 1) {
    racc  += __shfl_xor(racc, off, 64);
    vqacc += __shfl_xor(vqacc, off, 64);
  }
  __syncthreads();                       // all table reads done; smem reusable
  float* sc = (float*)smem;
  if (lane == 0) { sc[wave * 2] = racc; sc[wave * 2 + 1] = vqacc; }
  __syncthreads();
  int* flag = (int*)(smem + 512);
  if (tid == 0) {
    float R = 0.f, V = 0.f;
#pragma unroll
    for (int w = 0; w < WVS; ++w) { R += sc[2 * w]; V += sc[2 * w + 1]; }
    partials[blockIdx.x * 2]     = R;
    partials[blockIdx.x * 2 + 1] = V;
    __threadfence();                     // release partials device-wide
    unsigned t = atomicAdd(counter, 1u);
    *flag = (t == NBLK - 1) ? 1 : 0;
  }
  __syncthreads();
  if (*flag) {                           // last block finalizes (deterministic order)
    __threadfence();
    float r = 0.f, v = 0.f;
    if (tid < NBLK) { r = partials[2 * tid]; v = partials[2 * tid + 1]; }
#pragma unroll
    for (int off = 1; off < 64; off <<= 1) {
      r += __shfl_xor(r, off, 64);
      v += __shfl_xor(v, off, 64);
    }
    if (lane == 0) { sc[64 + wave * 2] = r; sc[64 + wave * 2 + 1] = v; }
    __syncthreads();
    if (tid == 0) {
      float R = 0.f, V = 0.f;
#pragma unroll
      for (int w = 0; w < 4; ++w) { R += sc[64 + 2 * w]; V += sc[64 + 2 * w + 1]; }
      out[7340032] = R * (1.0f / 7340032.0f);        // recon_loss = S / (B*28)
      out[7340033] = V * (1.25f / 16777216.0f);      // vq_loss = 1.25 * S / (B*64)
    }
  }
}

extern "C" void kernel_launch(void* const* d_in, const int* in_sizes, int n_in,
                              void* d_out, int out_size, void* d_ws, size_t ws_size,
                              hipStream_t stream) {
  const float* x   = (const float*)d_in[0];
  const float* ew1 = (const float*)d_in[1];
  const float* eb1 = (const float*)d_in[2];
  const float* ew2 = (const float*)d_in[3];
  const float* eb2 = (const float*)d_in[4];
  const float* cb  = (const float*)d_in[5];
  const float* dw1 = (const float*)d_in[6];
  const float* db1 = (const float*)d_in[7];
  const float* dw2 = (const float*)d_in[8];
  const float* db2 = (const float*)d_in[9];

  char* ws = (char*)d_ws;
  unsigned short* blob = (unsigned short*)(ws + 0);   // 131968 B
  float* partials = (float*)(ws + 132096);            // 256*2 f32 = 2048 B
  unsigned* counter = (unsigned*)(ws + 134144);       // 4 B

  float* out = (float*)d_out;

  // allow >64 KB dynamic LDS (gfx950 workgroup max is 160 KB)
  (void)hipFuncSetAttribute((const void*)vq_main,
                            hipFuncAttributeMaxDynamicSharedMemorySize, LDS_BYTES);

  (void)hipMemsetAsync(counter, 0, 4, stream);        // graph node: re-zeroed per replay
  vq_prep<<<(PREP_END + 255) / 256, 256, 0, stream>>>(
      ew1, eb1, ew2, eb2, cb, dw1, db1, dw2, db2, blob);
  vq_main<<<NBLK, 1024, LDS_BYTES, stream>>>(x, blob, out, partials, counter);
}

// Round 8
// 131.853 us; speedup vs baseline: 1.0930x; 1.0606x over previous
//
#include <hip/hip_runtime.h>

#define BATCH   262144
#define IN_DIM  28
#define HID     128
#define LAT     64
#define NCODES  512
#define NBLK    256             // 1024 rows per block (16 waves x 64 rows)
#define WVS     16
#define NWAVE   (NBLK * WVS)    // 4096

// ---- quad-grouped LDS table geometry ----
// Element (row,k) stored at row*S + q'*(K/4) + j*4 + e where k = j*16 + q'*4 + e.
// A lane (lm, quad) reads K/4 CONTIGUOUS shorts at row*S + quad*(K/4): pure
// ds_read_b128, 16B-aligned. Strides 40/72/136 shorts give 2-way bank aliasing
// only (free). Each v8s read covers TWO logical-k chunks -- which this round
// feeds to ONE mfma_16x16x32 instead of two mfma_16x16x16 (k-relabeling is
// valid because both operands use the same slot ordering).
#define S1 40     // lw1  [128][40]  K=32  (k>=28 zero)
#define S2 136    // lw2/ld2 [..][136] K=128
#define SC 72     // lcb/ld1 [..][72]  K=64
#define O_LW1 0
#define O_LW2 5120
#define O_LCB 13824
#define O_LD1 50688
#define O_LD2 59904
#define BLOB_SHORTS 64256
#define BLOB_F32    864
#define BLOB_BYTES  (BLOB_SHORTS * 2 + BLOB_F32 * 4)   // 131968
#define LDS_BYTES   BLOB_BYTES

// prep thread-index regions (e2 is 8-lane-parallel)
#define E2_BASE   BLOB_SHORTS            // 4096 threads (8 per code)
#define B1_BASE   (BLOB_SHORTS + 4096)
#define B2_BASE   (B1_BASE + 128)
#define DB1_BASE  (B2_BASE + 64)
#define DB2_BASE  (DB1_BASE + 128)
#define PREP_END  (DB2_BASE + 32)

typedef short v4s __attribute__((ext_vector_type(4)));
typedef short v8s __attribute__((ext_vector_type(8)));
typedef float v4f __attribute__((ext_vector_type(4)));

union u4v8 { unsigned u[4]; v8s s; };

__device__ __forceinline__ unsigned short f2bf(float f) {   // RNE (prep only)
  unsigned u = __float_as_uint(f);
  u += 0x7fffu + ((u >> 16) & 1u);
  return (unsigned short)(u >> 16);
}
// pack two truncated bf16 (hi, lo) in ONE v_perm_b32 (truncation validated r7/r8)
__device__ __forceinline__ unsigned pk(float hi, float lo) {
  return __builtin_amdgcn_perm(__float_as_uint(hi), __float_as_uint(lo), 0x07060302u);
}
// unpack truncated-bf16 lanes of a pk'd u32 back to f32 (for the loss diff)
__device__ __forceinline__ float xf0(unsigned u) { return __uint_as_float(u << 16); }
__device__ __forceinline__ float xf1(unsigned u) { return __uint_as_float(u & 0xFFFF0000u); }

// 16x16x32 bf16 MFMA. C-layout row = quad*4+r (shape-determined, same as x16),
// so chained stages keep working; the v8s B-operand is two pk'd register pairs.
__device__ __forceinline__ v4f mfma32(v8s a, v8s b, v4f c) {
  return __builtin_amdgcn_mfma_f32_16x16x32_bf16(a, b, c, 0, 0, 0);
}

__device__ __forceinline__ v8s rlpk2(v4f h0, v4f h1) {   // relu+pack 2 C-tiles
  u4v8 c;
  c.u[0] = pk(fmaxf(h0[1], 0.f), fmaxf(h0[0], 0.f));
  c.u[1] = pk(fmaxf(h0[3], 0.f), fmaxf(h0[2], 0.f));
  c.u[2] = pk(fmaxf(h1[1], 0.f), fmaxf(h1[0], 0.f));
  c.u[3] = pk(fmaxf(h1[3], 0.f), fmaxf(h1[2], 0.f));
  return c.s;
}
__device__ __forceinline__ v8s zpk2(v4f z0, v4f z1) {    // pack 2 C-tiles
  u4v8 c;
  c.u[0] = pk(z0[1], z0[0]); c.u[1] = pk(z0[3], z0[2]);
  c.u[2] = pk(z1[1], z1[0]); c.u[3] = pk(z1[3], z1[2]);
  return c.s;
}
__device__ __forceinline__ v8s mkv8(unsigned a, unsigned b, unsigned c2, unsigned d) {
  u4v8 c; c.u[0] = a; c.u[1] = b; c.u[2] = c2; c.u[3] = d; return c.s;
}
// argmin key: dist upper bits | 9-bit code (float order == dist order to 2^-14 rel;
// lowest code wins ties among equal upper bits)
__device__ __forceinline__ float kpack(float d, unsigned code) {
  return __uint_as_float((__float_as_uint(d) & 0xFFFFFE00u) | code);
}

// Blob layout (short offsets), quad-grouped, pad zeroed:
//   lw1 @0      [128 hid][40]   enc_w1^T   (K=32 slot, k>=28 zero)
//   lw2 @5120   [64  lat][136]  enc_w2^T   (K=128)
//   lcb @13824  [512 code][72]  bf16(-2*codebook) (K=64)
//   ld1 @50688  [128 hid][72]   bf16(-0.5*dec_w1^T)  (scale cancels -2q)
//   ld2 @59904  [32  n][136]    dec_w2^T   (rows n>=28 zero)
// f32 @ byte 128512: e2[512], b1[128], b2[64], db1[128], db2[32 pad0]
__global__ __launch_bounds__(256) void vq_prep(
    const float* __restrict__ ew1, const float* __restrict__ eb1,
    const float* __restrict__ ew2, const float* __restrict__ eb2,
    const float* __restrict__ cb,  const float* __restrict__ dw1,
    const float* __restrict__ db1, const float* __restrict__ dw2,
    const float* __restrict__ db2,
    unsigned short* __restrict__ blob) {
  int i = blockIdx.x * 256 + threadIdx.x;
  float* fb = (float*)(blob + BLOB_SHORTS);
  if (i < O_LW2) {                       // lw1 [128][40] K=32 per=8
    int row = i / S1, s = i % S1;
    unsigned short v = 0;
    if (s < 32) {
      int q = s >> 3, r2 = s & 7, j = r2 >> 2, e = r2 & 3;
      int k = j * 16 + q * 4 + e;
      if (k < IN_DIM) v = f2bf(ew1[k * HID + row]);
    }
    blob[i] = v;
  } else if (i < O_LCB) {                // lw2 [64][136] K=128 per=32
    int j2 = i - O_LW2; int row = j2 / S2, s = j2 % S2;
    unsigned short v = 0;
    if (s < 128) {
      int q = s >> 5, r2 = s & 31, j = r2 >> 2, e = r2 & 3;
      int k = j * 16 + q * 4 + e;
      v = f2bf(ew2[k * LAT + row]);
    }
    blob[i] = v;
  } else if (i < O_LD1) {                // lcb [512][72] K=64 per=16, = -2*cb
    int j2 = i - O_LCB; int row = j2 / SC, s = j2 % SC;
    unsigned short v = 0;
    if (s < 64) {
      int q = s >> 4, r2 = s & 15, j = r2 >> 2, e = r2 & 3;
      int k = j * 16 + q * 4 + e;
      v = f2bf(-2.0f * cb[row * LAT + k]);
    }
    blob[i] = v;
  } else if (i < O_LD2) {                // ld1 [128][72] = -0.5*dec_w1^T
    int j2 = i - O_LD1; int row = j2 / SC, s = j2 % SC;
    unsigned short v = 0;
    if (s < 64) {
      int q = s >> 4, r2 = s & 15, j = r2 >> 2, e = r2 & 3;
      int k = j * 16 + q * 4 + e;
      v = f2bf(-0.5f * dw1[k * HID + row]);
    }
    blob[i] = v;
  } else if (i < BLOB_SHORTS) {          // ld2 [32][136]
    int j2 = i - O_LD2; int row = j2 / S2, s = j2 % S2;
    unsigned short v = 0;
    if (s < 128 && row < IN_DIM) {
      int q = s >> 5, r2 = s & 31, j = r2 >> 2, e = r2 & 3;
      int k = j * 16 + q * 4 + e;
      v = f2bf(dw2[k * IN_DIM + row]);
    }
    blob[i] = v;
  } else if (i < B1_BASE) {              // e2: 8 lanes per code, float4 loads
    int j = i - E2_BASE;                 // wave-aligned region
    int c = j >> 3, l = j & 7;
    const float* p = cb + c * LAT + l * 8;
    float4 a = *(const float4*)p;
    float4 b = *(const float4*)(p + 4);
    float s = a.x * a.x + a.y * a.y + a.z * a.z + a.w * a.w
            + b.x * b.x + b.y * b.y + b.z * b.z + b.w * b.w;
    s += __shfl_xor(s, 1, 64);
    s += __shfl_xor(s, 2, 64);
    s += __shfl_xor(s, 4, 64);
    if (l == 0) fb[c] = s;
  } else if (i < B2_BASE) {
    fb[512 + (i - B1_BASE)] = eb1[i - B1_BASE];
  } else if (i < DB1_BASE) {
    fb[640 + (i - B2_BASE)] = eb2[i - B2_BASE];
  } else if (i < DB2_BASE) {
    fb[704 + (i - DB1_BASE)] = db1[i - DB1_BASE];
  } else if (i < PREP_END) {
    int k = i - DB2_BASE;
    fb[832 + k] = (k < IN_DIM) ? db2[k] : 0.f;
  }
}

// ---- 2-tile stage 1+2 (mfma32): x -> h -> z for tiles A and B, every weight
// fragment read ONCE, ONE mfma32 where r14 used two mfma16. jp-loop stays
// #pragma unroll 1 (the spill guard).
__device__ __forceinline__ void s12_pair(
    const unsigned short* __restrict__ L, const float* __restrict__ LF,
    int lm, int quad, v8s bxa, v8s bxb,
    v8s& zfa01, v8s& zfa23, v8s& zfb01, v8s& zfb23,
    float& z2a, float& z2b) {
  const int fw1 = O_LW1 + lm * S1 + quad * 8;
  const int fw2 = O_LW2 + lm * S2 + quad * 32;
  v4f za[4], zb[4];
#pragma unroll
  for (int nt = 0; nt < 4; ++nt) {
    v4f s = *(const v4f*)&LF[640 + nt * 16 + quad * 4];      // b2 seed (broadcast)
    za[nt] = s; zb[nt] = s;
  }
#pragma unroll 1
  for (int jp = 0; jp < 4; ++jp) {
    v8s hA, hB;
    {
      v8s w0 = *(const v8s*)&L[fw1 + (2 * jp) * (16 * S1)];
      v4f s0 = *(const v4f*)&LF[512 + (2 * jp) * 16 + quad * 4];     // b1 seed
      v8s w1 = *(const v8s*)&L[fw1 + (2 * jp + 1) * (16 * S1)];
      v4f s1 = *(const v4f*)&LF[512 + (2 * jp + 1) * 16 + quad * 4];
      v4f h0a = mfma32(w0, bxa, s0);
      v4f h1a = mfma32(w1, bxa, s1);
      v4f h0b = mfma32(w0, bxb, s0);
      v4f h1b = mfma32(w1, bxb, s1);
      hA = rlpk2(h0a, h1a);
      hB = rlpk2(h0b, h1b);
    }
#pragma unroll
    for (int nt = 0; nt < 4; ++nt) {
      v8s w2 = *(const v8s*)&L[fw2 + nt * (16 * S2) + jp * 8];
      za[nt] = mfma32(w2, hA, za[nt]);
      zb[nt] = mfma32(w2, hB, zb[nt]);
    }
  }
  z2a = za[0][0] * za[0][0] + za[0][1] * za[0][1] + za[0][2] * za[0][2] + za[0][3] * za[0][3]
      + za[1][0] * za[1][0] + za[1][1] * za[1][1] + za[1][2] * za[1][2] + za[1][3] * za[1][3]
      + za[2][0] * za[2][0] + za[2][1] * za[2][1] + za[2][2] * za[2][2] + za[2][3] * za[2][3]
      + za[3][0] * za[3][0] + za[3][1] * za[3][1] + za[3][2] * za[3][2] + za[3][3] * za[3][3];
  z2b = zb[0][0] * zb[0][0] + zb[0][1] * zb[0][1] + zb[0][2] * zb[0][2] + zb[0][3] * zb[0][3]
      + zb[1][0] * zb[1][0] + zb[1][1] * zb[1][1] + zb[1][2] * zb[1][2] + zb[1][3] * zb[1][3]
      + zb[2][0] * zb[2][0] + zb[2][1] * zb[2][1] + zb[2][2] * zb[2][2] + zb[2][3] * zb[2][3]
      + zb[3][0] * zb[3][0] + zb[3][1] * zb[3][1] + zb[3][2] * zb[3][2] + zb[3][3] * zb[3][3];
  zfa01 = zpk2(za[0], za[1]); zfa23 = zpk2(za[2], za[3]);
  zfb01 = zpk2(zb[0], zb[1]); zfb23 = zpk2(zb[2], zb[3]);
}

// ---- 2-tile stage 5+6 (mfma32): q -> hd -> recon, fragments shared;
// stores + loss (x from bf16 packs).
__device__ __forceinline__ void s56_pair(
    const unsigned short* __restrict__ L, const float* __restrict__ LF,
    int lm, int quad, int codeA, int codeB,
    unsigned xa0, unsigned xa1, unsigned xa2, unsigned xa3,
    unsigned xb0, unsigned xb1, unsigned xb2, unsigned xb3,
    float* __restrict__ orowA, float* __restrict__ orowB, float& racc) {
  const int fd1 = O_LD1 + lm * SC + quad * 16;
  const int fd2 = O_LD2 + lm * S2 + quad * 32;
  const int gA = O_LCB + codeA * SC + quad * 16;   // -2q rows (wave-uniform code)
  const int gB = O_LCB + codeB * SC + quad * 16;
  v8s qa0 = *(const v8s*)&L[gA];
  v8s qa1 = *(const v8s*)&L[gA + 8];
  v8s qb0 = *(const v8s*)&L[gB];
  v8s qb1 = *(const v8s*)&L[gB + 8];
  v4f a6a[2], a6b[2];
#pragma unroll
  for (int nt = 0; nt < 2; ++nt) {
    v4f s = *(const v4f*)&LF[832 + nt * 16 + quad * 4];      // db2 seed
    a6a[nt] = s; a6b[nt] = s;
  }
#pragma unroll 1
  for (int jp = 0; jp < 4; ++jp) {
    v8s hA, hB;
    {
      int j0 = 2 * jp;
      v8s d00 = *(const v8s*)&L[fd1 + j0 * (16 * SC)];
      v8s d01 = *(const v8s*)&L[fd1 + j0 * (16 * SC) + 8];
      v4f s0 = *(const v4f*)&LF[704 + j0 * 16 + quad * 4];   // db1 seed
      v8s d10 = *(const v8s*)&L[fd1 + (j0 + 1) * (16 * SC)];
      v8s d11 = *(const v8s*)&L[fd1 + (j0 + 1) * (16 * SC) + 8];
      v4f s1 = *(const v4f*)&LF[704 + (j0 + 1) * 16 + quad * 4];
      v4f h0 = mfma32(d00, qa0, s0);
      h0 = mfma32(d01, qa1, h0);
      v4f h1 = mfma32(d10, qa0, s1);
      h1 = mfma32(d11, qa1, h1);
      hA = rlpk2(h0, h1);
      h0 = mfma32(d00, qb0, s0);
      h0 = mfma32(d01, qb1, h0);
      h1 = mfma32(d10, qb0, s1);
      h1 = mfma32(d11, qb1, h1);
      hB = rlpk2(h0, h1);
    }
#pragma unroll
    for (int nt = 0; nt < 2; ++nt) {
      v8s w6 = *(const v8s*)&L[fd2 + nt * (16 * S2) + jp * 8];
      a6a[nt] = mfma32(w6, hA, a6a[nt]);
      a6b[nt] = mfma32(w6, hB, a6b[nt]);
    }
  }
  *(float4*)(orowA + quad * 4) = (float4){a6a[0][0], a6a[0][1], a6a[0][2], a6a[0][3]};
  *(float4*)(orowB + quad * 4) = (float4){a6b[0][0], a6b[0][1], a6b[0][2], a6b[0][3]};
  if (quad < 3) {
    *(float4*)(orowA + 16 + quad * 4) = (float4){a6a[1][0], a6a[1][1], a6a[1][2], a6a[1][3]};
    *(float4*)(orowB + 16 + quad * 4) = (float4){a6b[1][0], a6b[1][1], a6b[1][2], a6b[1][3]};
  }
  float d;
  d = a6a[0][0] - xf0(xa0); racc += d * d;
  d = a6a[0][1] - xf1(xa0); racc += d * d;
  d = a6a[0][2] - xf0(xa1); racc += d * d;
  d = a6a[0][3] - xf1(xa1); racc += d * d;
  d = a6a[1][0] - xf0(xa2); racc += d * d;   // quad3: a6[1]==0 and x==0
  d = a6a[1][1] - xf1(xa2); racc += d * d;
  d = a6a[1][2] - xf0(xa3); racc += d * d;
  d = a6a[1][3] - xf1(xa3); racc += d * d;
  d = a6b[0][0] - xf0(xb0); racc += d * d;
  d = a6b[0][1] - xf1(xb0); racc += d * d;
  d = a6b[0][2] - xf0(xb1); racc += d * d;
  d = a6b[0][3] - xf1(xb1); racc += d * d;
  d = a6b[1][0] - xf0(xb2); racc += d * d;
  d = a6b[1][1] - xf1(xb2); racc += d * d;
  d = a6b[1][2] - xf0(xb3); racc += d * d;
  d = a6b[1][3] - xf1(xb3); racc += d * d;
}

// ---------------- fused main kernel ----------------
// Round-17: r14 structure EXACTLY (3-kernel graph -- r16 measured the in-kernel
// finalize at +9.6us main, reverted) + every adjacent mfma16 PAIR collapsed to
// ONE mfma_f32_16x16x32_bf16 (448 -> 224 MFMA/sweep). Valid because every v8s
// table read already holds the two logical-k chunks in the same slot order as
// the paired B registers (k-relabeling invariance). Same FLOPs, same LDS
// traffic, half the MFMA issue slots -- targets the issue/latency bound.
__global__ __attribute__((amdgpu_flat_work_group_size(1024, 1024)))
__attribute__((amdgpu_waves_per_eu(4, 4)))
void vq_main(
    const float* __restrict__ x,
    const unsigned short* __restrict__ blob,
    float* __restrict__ out, float* __restrict__ partials) {

  extern __shared__ __align__(16) char smem[];
  const unsigned short* L = (const unsigned short*)smem;
  const float*         LF = (const float*)(smem + BLOB_SHORTS * 2);

  const int tid  = threadIdx.x;
  const int wave = tid >> 6;
  const int lane = tid & 63;
  const int quad = lane >> 4;
  const int lm   = lane & 15;

  // ---- stage tables into LDS (one-time) ----
  {
    const float4* src = (const float4*)blob;
    float4* dst = (float4*)smem;
#pragma unroll
    for (int it = 0; it < 9; ++it) {
      int idx = it * 1024 + tid;
      if (idx < BLOB_BYTES / 16) dst[idx] = src[idx];
    }
  }
  __syncthreads();

  const int rbase = blockIdx.x * 1024 + wave * 64;
  float racc = 0.f, vqacc = 0.f;

#pragma unroll 1
  for (int sw = 0; sw < 2; ++sw) {
    const int r0 = rbase + sw * 32;

    // ---- x load -> packed bf16 only (f32 temps die immediately) ----
    unsigned xa0, xa1, xa2, xa3, xb0, xb1, xb2, xb3;
    {
      const float* xpa = x + (size_t)(r0 + lm) * IN_DIM;
      const float* xpb = x + (size_t)(r0 + 16 + lm) * IN_DIM;
      float4 t = *(const float4*)(xpa + quad * 4);
      xa0 = pk(t.y, t.x); xa1 = pk(t.w, t.z);
      t = (quad < 3) ? *(const float4*)(xpa + 16 + quad * 4) : (float4){0.f, 0.f, 0.f, 0.f};
      xa2 = pk(t.y, t.x); xa3 = pk(t.w, t.z);
      t = *(const float4*)(xpb + quad * 4);
      xb0 = pk(t.y, t.x); xb1 = pk(t.w, t.z);
      t = (quad < 3) ? *(const float4*)(xpb + 16 + quad * 4) : (float4){0.f, 0.f, 0.f, 0.f};
      xb2 = pk(t.y, t.x); xb3 = pk(t.w, t.z);
    }

    // ---- stages 1+2, tiles A+B together (fragments shared, mfma32) ----
    v8s zfa01, zfa23, zfb01, zfb23;
    float z2a, z2b;
    s12_pair(L, LF, lm, quad,
             mkv8(xa0, xa1, xa2, xa3), mkv8(xb0, xb1, xb2, xb3),
             zfa01, zfa23, zfb01, zfb23, z2a, z2b);
    __builtin_amdgcn_sched_barrier(0);

    // ---- argmin: dist^T = e2 + (-2e)·z; cb fragments SHARED by both tiles ----
    const int fcb = O_LCB + lm * SC + quad * 16;
    float bkA = __uint_as_float(0x7f7fffffu);
    float bkB = bkA;
#pragma unroll 2
    for (int ct = 0; ct < 32; ++ct) {
      v8s c0 = *(const v8s*)&L[fcb + ct * (16 * SC)];        // k-chunks 0,1
      v8s c1 = *(const v8s*)&L[fcb + ct * (16 * SC) + 8];    // k-chunks 2,3
      v4f sd = *(const v4f*)&LF[ct * 16 + quad * 4];         // e2 seed
      v4f dA = mfma32(c0, zfa01, sd);
      dA = mfma32(c1, zfa23, dA);
      v4f dB = mfma32(c0, zfb01, sd);
      dB = mfma32(c1, zfb23, dB);
      unsigned cbase = (unsigned)(ct * 16 + quad * 4);
      bkA = fminf(bkA, fminf(fminf(kpack(dA[0], cbase), kpack(dA[1], cbase + 1)),
                             fminf(kpack(dA[2], cbase + 2), kpack(dA[3], cbase + 3))));
      bkB = fminf(bkB, fminf(fminf(kpack(dB[0], cbase), kpack(dB[1], cbase + 1)),
                             fminf(kpack(dB[2], cbase + 2), kpack(dB[3], cbase + 3))));
    }

    // ---- cross-quad argmin + z2 reduce ----
#pragma unroll
    for (int off = 16; off < 64; off <<= 1) {
      bkA = fminf(bkA, __shfl_xor(bkA, off, 64));
      bkB = fminf(bkB, __shfl_xor(bkB, off, 64));
      z2a += __shfl_xor(z2a, off, 64);
      z2b += __shfl_xor(z2b, off, 64);
    }
    unsigned ka = __float_as_uint(bkA), kb = __float_as_uint(bkB);
    int codeA = (int)(ka & 511u), codeB = (int)(kb & 511u);
    if (quad == 0)
      vqacc += z2a + __uint_as_float(ka & 0xFFFFFE00u)
             + z2b + __uint_as_float(kb & 0xFFFFFE00u);      // ||z-q||^2
    __builtin_amdgcn_sched_barrier(0);

    // ---- stages 5+6 + store + loss, tiles A+B together (mfma32) ----
    s56_pair(L, LF, lm, quad, codeA, codeB,
             xa0, xa1, xa2, xa3, xb0, xb1, xb2, xb3,
             out + (size_t)(r0 + lm) * IN_DIM,
             out + (size_t)(r0 + 16 + lm) * IN_DIM, racc);
    __builtin_amdgcn_sched_barrier(0);
  }

  // ---- per-wave butterfly, per-wave partial store (no atomics) ----
#pragma unroll
  for (int off = 1; off < 64; off <<= 1) {
    racc  += __shfl_xor(racc, off, 64);
    vqacc += __shfl_xor(vqacc, off, 64);
  }
  if (lane == 0) {
    size_t w = (size_t)blockIdx.x * WVS + wave;
    partials[w * 2]     = racc;
    partials[w * 2 + 1] = vqacc;
  }
}

// ---------------- finalize: reduce per-wave partials, write scalars ----------------
__global__ __launch_bounds__(256) void vq_fin(const float* __restrict__ partials,
                                              float* __restrict__ out) {
  float r = 0.f, v = 0.f;
  for (int i = threadIdx.x; i < NWAVE; i += 256) {
    r += partials[2 * i];
    v += partials[2 * i + 1];
  }
#pragma unroll
  for (int off = 1; off < 64; off <<= 1) {
    r += __shfl_xor(r, off, 64);
    v += __shfl_xor(v, off, 64);
  }
  __shared__ float s[4][2];
  int w = threadIdx.x >> 6;
  if ((threadIdx.x & 63) == 0) { s[w][0] = r; s[w][1] = v; }
  __syncthreads();
  if (threadIdx.x == 0) {
    float R = s[0][0] + s[1][0] + s[2][0] + s[3][0];
    float V = s[0][1] + s[1][1] + s[2][1] + s[3][1];
    out[7340032] = R * (1.0f / 7340032.0f);          // recon_loss = S / (B*28)
    out[7340033] = V * (1.25f / 16777216.0f);        // vq_loss = 1.25 * S / (B*64)
  }
}

extern "C" void kernel_launch(void* const* d_in, const int* in_sizes, int n_in,
                              void* d_out, int out_size, void* d_ws, size_t ws_size,
                              hipStream_t stream) {
  const float* x   = (const float*)d_in[0];
  const float* ew1 = (const float*)d_in[1];
  const float* eb1 = (const float*)d_in[2];
  const float* ew2 = (const float*)d_in[3];
  const float* eb2 = (const float*)d_in[4];
  const float* cb  = (const float*)d_in[5];
  const float* dw1 = (const float*)d_in[6];
  const float* db1 = (const float*)d_in[7];
  const float* dw2 = (const float*)d_in[8];
  const float* db2 = (const float*)d_in[9];

  char* ws = (char*)d_ws;
  unsigned short* blob = (unsigned short*)(ws + 0);   // 131968 B
  float* partials = (float*)(ws + 132096);            // 32768 B (4096*2 f32)

  float* out = (float*)d_out;

  // allow >64 KB dynamic LDS (gfx950 workgroup max is 160 KB)
  (void)hipFuncSetAttribute((const void*)vq_main,
                            hipFuncAttributeMaxDynamicSharedMemorySize, LDS_BYTES);

  vq_prep<<<(PREP_END + 255) / 256, 256, 0, stream>>>(
      ew1, eb1, ew2, eb2, cb, dw1, db1, dw2, db2, blob);
  vq_main<<<NBLK, 1024, LDS_BYTES, stream>>>(x, blob, out, partials);
  vq_fin<<<1, 256, 0, stream>>>(partials, out);
}